// Round 9
// baseline (477.766 us; speedup 1.0000x reference)
//
#include <hip/hip_runtime.h>

// LSTM: B=2048, T=512, INPUT=2, H=32, OUT=1.
// Round 9: TWO batch elements per wave (1024 waves, 1 wave/SIMD) — the two
// independent recurrences are statically interleaved so each chain's stalls
// (trans latency, readlane, shfl) are filled by the other's instructions.
// R4/R8 ran 2 waves/SIMD in near-lockstep and idled 22-34% of issue slots.
// Weights are SHARED between the two elements (same gate rows per lane).
// h state: 2 x 16 SGPR f32-pairs fed to v_pk_fma_f32 as scalar src0
// (pk_fma is HALF-RATE: 4cyc — packing saves instruction count only).
// x is software-prefetched one full step ahead (x-proj folded in after the
// dot), so the LDS x-read latency is never on the critical path.

#define BB 2048
#define TT 512
#define HH 32
#define CHUNK 64
#define HROW 33   // hist row stride: banks (lane+u)%32 -> 2-way alias = free

typedef float v2f __attribute__((ext_vector_type(2)));

__device__ __forceinline__ float sigm(float x) {
    return __builtin_amdgcn_rcpf(1.0f + __expf(-x));
}

// acc += h2 * w  (packed f32; h2 = {h_even, h_odd} in an SGPR pair)
__device__ __forceinline__ v2f pkfma_s(v2f acc, unsigned long long h2, v2f w) {
    asm("v_pk_fma_f32 %0, %1, %2, %0" : "+v"(acc) : "s"(h2), "v"(w));
    return acc;
}

__device__ __forceinline__ unsigned long long rl_pair(float v, int k) {
    unsigned lo = (unsigned)__builtin_amdgcn_readlane(__float_as_int(v), 2 * k);
    unsigned hi = (unsigned)__builtin_amdgcn_readlane(__float_as_int(v), 2 * k + 1);
    return ((unsigned long long)hi << 32) | lo;
}

__global__ __launch_bounds__(128, 1) void lstm_fused_kernel(
    const float* __restrict__ x,     // [B, T, 2]
    const float* __restrict__ W_ih,  // [128, 2]
    const float* __restrict__ W_hh,  // [128, 32]
    const float* __restrict__ b_ih,  // [128]
    const float* __restrict__ b_hh,  // [128]
    const float* __restrict__ W_fc,  // [1, 32]
    const float* __restrict__ b_fc,  // [1]
    float* __restrict__ out)         // [B, T, 1]
{
    __shared__ float lds_x[4 * TT * 2];        // 16 KB: 4 elems/block x staging
    __shared__ float lds_h[4 * CHUNK * HROW];  // 33 KB: 4 elems FC history

    const int lane = threadIdx.x & 63;
    const int wv   = threadIdx.x >> 6;          // 0..1
    const int e0   = blockIdx.x * 4 + wv * 2;   // this wave's two elements
    const bool low = (lane < 32);

    // ---- stage x for both elements, coalesced float4 ----
    {
        const float4* xg0 = (const float4*)(x + (size_t)e0 * TT * 2);
        const float4* xg1 = (const float4*)(x + (size_t)(e0 + 1) * TT * 2);
        float4* xs0 = (float4*)(lds_x + (wv * 2 + 0) * TT * 2);
        float4* xs1 = (float4*)(lds_x + (wv * 2 + 1) * TT * 2);
        #pragma unroll
        for (int r = 0; r < 4; ++r) {
            xs0[r * 64 + lane] = xg0[r * 64 + lane];
            xs1[r * 64 + lane] = xg1[r * 64 + lane];
        }
    }

    // ---- per-lane weights (shared by both elements) ----
    const int rlo = lane, rhi = lane + 64;
    const v2f wihl = ((const v2f*)W_ih)[rlo];
    const v2f wihh = ((const v2f*)W_ih)[rhi];
    const float bl = b_ih[rlo] + b_hh[rlo];
    const float bh = b_ih[rhi] + b_hh[rhi];

    v2f wloq[HH / 2], whiq[HH / 2];
    #pragma unroll
    for (int k = 0; k < HH / 2; ++k) {
        wloq[k] = ((const v2f*)(W_hh + rlo * HH))[k];
        whiq[k] = ((const v2f*)(W_hh + rhi * HH))[k];
    }

    float wfc[HH];
    #pragma unroll
    for (int u = 0; u < HH; ++u) wfc[u] = W_fc[u];
    const float bfc = b_fc[0];

    // activation selectors: lanes<32 hi-gate = tanh (=2*sigm(2x)-1)
    const float Mm = low ? 2.0f : 1.0f;
    const float Aa = low ? 2.0f : 1.0f;
    const float Bb = low ? -1.0f : 0.0f;

    float c0 = 0.0f, c1 = 0.0f;
    unsigned long long h0[HH / 2], h1[HH / 2];   // f32 pairs, wave-uniform
    #pragma unroll
    for (int k = 0; k < HH / 2; ++k) { h0[k] = 0ull; h1[k] = 0ull; }

    float* out0 = out + (size_t)e0 * TT;
    float* out1 = out + (size_t)(e0 + 1) * TT;
    const v2f* xw0 = (const v2f*)(lds_x + (wv * 2 + 0) * TT * 2);
    const v2f* xw1 = (const v2f*)(lds_x + (wv * 2 + 1) * TT * 2);
    float* hb0 = lds_h + (wv * 2 + 0) * CHUNK * HROW;
    float* hb1 = lds_h + (wv * 2 + 1) * CHUNK * HROW;
    // combined hist write target: low lanes -> elem0, high -> elem1
    float* hwr = (low ? hb0 : hb1) + (lane & 31);

    __syncthreads();

    // prime the x prefetch pipeline
    v2f xt0 = xw0[0], xt1 = xw1[0];

    #pragma unroll 1
    for (int ch = 0; ch < TT / CHUNK; ++ch) {
        #pragma unroll 2
        for (int u = 0; u < CHUNK; ++u) {
            const int tn = (ch * CHUNK + u + 1) & (TT - 1);
            v2f xt0n = xw0[tn];              // prefetch next step's x
            v2f xt1n = xw1[tn];              // (latency hidden under the dot)

            // recurrent dots: 8 independent chains (4 per element), depth 8
            v2f aL0 = {0,0}, aL1 = {0,0}, aH0 = {0,0}, aH1 = {0,0};
            v2f bL0 = {0,0}, bL1 = {0,0}, bH0 = {0,0}, bH1 = {0,0};
            #pragma unroll
            for (int k = 0; k < HH / 4; ++k) {
                aL0 = pkfma_s(aL0, h0[k],          wloq[k]);
                bL0 = pkfma_s(bL0, h1[k],          wloq[k]);
                aH0 = pkfma_s(aH0, h0[k],          whiq[k]);
                bH0 = pkfma_s(bH0, h1[k],          whiq[k]);
                aL1 = pkfma_s(aL1, h0[k + HH/4],   wloq[k + HH/4]);
                bL1 = pkfma_s(bL1, h1[k + HH/4],   wloq[k + HH/4]);
                aH1 = pkfma_s(aH1, h0[k + HH/4],   whiq[k + HH/4]);
                bH1 = pkfma_s(bH1, h1[k + HH/4],   whiq[k + HH/4]);
            }

            // x-projection + bias (current step's x, loaded last iteration)
            float xpL0 = fmaf(xt0.x, wihl.x, fmaf(xt0.y, wihl.y, bl));
            float xpH0 = fmaf(xt0.x, wihh.x, fmaf(xt0.y, wihh.y, bh));
            float xpL1 = fmaf(xt1.x, wihl.x, fmaf(xt1.y, wihl.y, bl));
            float xpH1 = fmaf(xt1.x, wihh.x, fmaf(xt1.y, wihh.y, bh));

            v2f sL0 = aL0 + aL1, sH0 = aH0 + aH1;
            v2f sL1 = bL0 + bL1, sH1 = bH0 + bH1;
            float glo0 = sL0.x + sL0.y + xpL0;
            float ghi0 = sH0.x + sH0.y + xpH0;
            float glo1 = sL1.x + sL1.y + xpL1;
            float ghi1 = sH1.x + sH1.y + xpH1;

            float alo0 = sigm(glo0);                     // i (low) / f (high)
            float ahi0 = fmaf(Aa, sigm(Mm * ghi0), Bb);  // tanh g / sigmoid o
            float alo1 = sigm(glo1);
            float ahi1 = fmaf(Aa, sigm(Mm * ghi1), Bb);

            float p00 = __shfl_xor(alo0, 32);
            float p10 = __shfl_xor(ahi0, 32);
            float p01 = __shfl_xor(alo1, 32);
            float p11 = __shfl_xor(ahi1, 32);

            float iv0 = low ? alo0 : p00;
            float fv0 = low ? p00  : alo0;
            float gv0 = low ? ahi0 : p10;
            float ov0 = low ? p10  : ahi0;
            float iv1 = low ? alo1 : p01;
            float fv1 = low ? p01  : alo1;
            float gv1 = low ? ahi1 : p11;
            float ov1 = low ? p11  : ahi1;

            c0 = fmaf(fv0, c0, iv0 * gv0);
            c1 = fmaf(fv1, c1, iv1 * gv1);
            float tc0 = fmaf(2.0f, sigm(2.0f * c0), -1.0f);
            float tc1 = fmaf(2.0f, sigm(2.0f * c1), -1.0f);
            float hn0 = ov0 * tc0;                       // valid on ALL lanes
            float hn1 = ov1 * tc1;

            // one combined hist write (2-way bank alias = free)
            hwr[u * HROW] = low ? hn0 : hn1;

            xt0 = xt0n; xt1 = xt1n;

            // broadcast both h vectors: 64 readlanes -> 32 SGPR pairs
            #pragma unroll
            for (int k = 0; k < HH / 2; ++k) {
                h0[k] = rl_pair(hn0, k);
                h1[k] = rl_pair(hn1, k);
            }
        }

        // ---- chunk flush: FC for 64 timesteps x 2 elements, coalesced ----
        float acc0 = bfc, acc1 = bfc;
        const float* r0 = hb0 + lane * HROW;
        const float* r1 = hb1 + lane * HROW;
        #pragma unroll
        for (int u2 = 0; u2 < HH; ++u2) {
            acc0 = fmaf(r0[u2], wfc[u2], acc0);
            acc1 = fmaf(r1[u2], wfc[u2], acc1);
        }
        out0[ch * CHUNK + lane] = acc0;
        out1[ch * CHUNK + lane] = acc1;
    }
}

extern "C" void kernel_launch(void* const* d_in, const int* in_sizes, int n_in,
                              void* d_out, int out_size, void* d_ws, size_t ws_size,
                              hipStream_t stream) {
    const float* x    = (const float*)d_in[0];
    const float* W_ih = (const float*)d_in[1];
    const float* W_hh = (const float*)d_in[2];
    const float* b_ih = (const float*)d_in[3];
    const float* b_hh = (const float*)d_in[4];
    const float* W_fc = (const float*)d_in[5];
    const float* b_fc = (const float*)d_in[6];
    float* out = (float*)d_out;

    dim3 grid(BB / 4);   // 512 blocks x 2 waves x 2 elements = 2048
    dim3 block(128);
    lstm_fused_kernel<<<grid, block, 0, stream>>>(x, W_ih, W_hh, b_ih, b_hh,
                                                  W_fc, b_fc, out);
}